// Round 6
// baseline (1364.297 us; speedup 1.0000x reference)
//
#include <hip/hip_runtime.h>
#include <math.h>

#define B_    32768
#define LN10_ 2.302585092994046f
#define MT_H  264   // padded m-tile count for sorted head GEMMs (>= 258 worst case)

typedef __attribute__((ext_vector_type(8))) short short8;
typedef __attribute__((ext_vector_type(4))) float f32x4;

typedef const __attribute__((address_space(1))) void gvoid_t;
typedef __attribute__((address_space(3))) void svoid_t;

__device__ __forceinline__ void gl16(const void* g, void* l) {
  __builtin_amdgcn_global_load_lds((gvoid_t*)g, (svoid_t*)l, 16, 0, 0);
}

__device__ __forceinline__ float bf2f(unsigned int u) {
  union { unsigned int i; float f; } v; v.i = u << 16; return v.f;
}
// round-to-nearest-even f32 -> bf16 (finite inputs)
__device__ __forceinline__ unsigned short f2bf(float f) {
  union { float f; unsigned int i; } v; v.f = f;
  unsigned int x = v.i;
  unsigned int r = x + 0x7FFFu + ((x >> 16) & 1u);
  return (unsigned short)(r >> 16);
}

// ---------------- GEMM: C[m,n] = sum_k A[m,k] * W[n,k]  (+bias, +elu, +col-stats)
// bf16 in/out, fp32 acc. grid: (N/128, Mtiles, E), block 256. Tile 128x128x64.
// LDS XOR swizzle (R4: SQ_LDS_BANK_CONFLICT 5e7 -> 0).
// XCD block swizzle (R4: big-GEMM FETCH 532 -> 131 MB ~= ideal); needs ny%8==0.
// Expert selection: e = texp ? texp[mt] : blockIdx.z; e<0 -> whole block exits
// (uniform). Strides eA/eW/eC/eBias are applied with e.
__global__ __launch_bounds__(256)
void gemm_bt(const unsigned short* __restrict__ A0, int lda,
             const unsigned short* __restrict__ W0, int ldw,
             unsigned short* __restrict__ C0, int ldc,
             int K, const float* __restrict__ bias0, int elu,
             float* __restrict__ st, int Ntot,
             long eA, long eW, long eC, int eBias,
             const int* __restrict__ texp) {
  __shared__ __align__(16) unsigned short lA[128 * 64];
  __shared__ __align__(16) unsigned short lB[128 * 64];
  const int t = threadIdx.x;
  const int nx = gridDim.x, ny = gridDim.y;
  const int f = blockIdx.y * nx + blockIdx.x;
  const int xcd = f & 7, g = f >> 3;
  const int gdiv = g / nx;
  const int mt = xcd * (ny >> 3) + gdiv;
  const int nt = g - gdiv * nx;
  const int mBase = mt * 128;
  const int nBase = nt * 128;
  int e = texp ? texp[mt] : (int)blockIdx.z;
  if (e < 0) return;  // pad tile, uniform exit
  const unsigned short* A = A0 + (size_t)e * eA;
  const unsigned short* W = W0 + (size_t)e * eW;
  unsigned short* C = C0 + (size_t)e * eC;
  const float* bias = bias0 ? (bias0 + (size_t)e * eBias) : nullptr;
  const unsigned short* Ap = A + (size_t)mBase * lda;
  const unsigned short* Wp = W + (size_t)nBase * ldw;
  const int w = t >> 6, l = t & 63;
  const int wr = (w >> 1) * 64, wc = (w & 1) * 64;
  const int lm = l & 15, lg = l >> 4;

  f32x4 acc[4][4];
#pragma unroll
  for (int i = 0; i < 4; ++i)
#pragma unroll
    for (int j = 0; j < 4; ++j) {
      f32x4 z4 = {0.f, 0.f, 0.f, 0.f};
      acc[i][j] = z4;
    }

  for (int k0 = 0; k0 < K; k0 += 64) {
    __syncthreads();
#pragma unroll
    for (int it = 0; it < 4; ++it) {
      int chunk = it * 256 + t;
      int row = chunk >> 3, sc = chunk & 7;
      int gc = (sc ^ (row & 7)) << 3;  // swizzled source chunk (element offset)
      gl16(Ap + (size_t)row * lda + k0 + gc, &lA[chunk * 8]);
      gl16(Wp + (size_t)row * ldw + k0 + gc, &lB[chunk * 8]);
    }
    __syncthreads();
#pragma unroll
    for (int kk = 0; kk < 64; kk += 32) {
      short8 af[4], bfr[4];
#pragma unroll
      for (int i = 0; i < 4; ++i) {
        int ar = wr + i * 16 + lm;
        int ac = (kk >> 3) + lg;
        af[i] = *(const short8*)&lA[ar * 64 + ((ac ^ (ar & 7)) << 3)];
      }
#pragma unroll
      for (int j = 0; j < 4; ++j) {
        int br = wc + j * 16 + lm;
        int bc = (kk >> 3) + lg;
        bfr[j] = *(const short8*)&lB[br * 64 + ((bc ^ (br & 7)) << 3)];
      }
#pragma unroll
      for (int i = 0; i < 4; ++i)
#pragma unroll
        for (int j = 0; j < 4; ++j)
          acc[i][j] = __builtin_amdgcn_mfma_f32_16x16x32_bf16(af[i], bfr[j], acc[i][j], 0, 0, 0);
    }
  }

  // epilogue: D row = (lane>>4)*4 + reg, col = lane&15
#pragma unroll
  for (int j = 0; j < 4; ++j) {
    int n = nBase + wc + j * 16 + lm;
    float bj = bias ? bias[n] : 0.f;
    float s = 0.f, q = 0.f;
#pragma unroll
    for (int i = 0; i < 4; ++i) {
      int m0 = mBase + wr + i * 16 + lg * 4;
#pragma unroll
      for (int r = 0; r < 4; ++r) {
        float v = acc[i][j][r] + bj;
        if (elu) v = v > 0.f ? v : expm1f(v);
        s += v; q += v * v;
        C[(size_t)(m0 + r) * ldc + n] = f2bf(v);
      }
    }
    if (st) {
      s += __shfl_xor(s, 16, 64); s += __shfl_xor(s, 32, 64);
      q += __shfl_xor(q, 16, 64); q += __shfl_xor(q, 32, 64);
      if (lg == 0) { atomicAdd(&st[n], s); atomicAdd(&st[Ntot + n], q); }
    }
  }
}

// ---------------- in-place BN + ELU on bf16 [B,N], 8 elems/thread (N pow2)
__global__ void bn_apply(unsigned short* __restrict__ Y, const float* __restrict__ st,
                         const float* __restrict__ gam, const float* __restrict__ bet,
                         int N, float invB) {
  size_t i = (size_t)blockIdx.x * blockDim.x + threadIdx.x;
  size_t base = i * 8;
  int col = (int)(base & (size_t)(N - 1));
  float a8[8], b8[8];
#pragma unroll
  for (int k = 0; k < 8; ++k) {
    int c = col + k;
    float m = st[c] * invB;
    float var = st[N + c] * invB - m * m;
    float av = gam[c] * rsqrtf(var + 1e-5f);
    a8[k] = av;
    b8[k] = bet[c] - m * av;
  }
  uint4 u = *(uint4*)&Y[base];
  unsigned int uu[4] = {u.x, u.y, u.z, u.w};
  unsigned int oo[4];
#pragma unroll
  for (int k = 0; k < 4; ++k) {
    float vlo = bf2f(uu[k] & 0xFFFFu);
    float vhi = bf2f(uu[k] >> 16);
    float flo = a8[2 * k] * vlo + b8[2 * k];
    float fhi = a8[2 * k + 1] * vhi + b8[2 * k + 1];
    flo = flo > 0.f ? flo : expm1f(flo);
    fhi = fhi > 0.f ? fhi : expm1f(fhi);
    oo[k] = (unsigned int)f2bf(flo) | ((unsigned int)f2bf(fhi) << 16);
  }
  uint4 o = {oo[0], oo[1], oo[2], oo[3]};
  *(uint4*)&Y[base] = o;
}

// ---------------- cast ALL weights fp32->bf16 in one launch (region table in
// float4 units; dst bf16 buffers contiguous in same order)
__global__ void cast_all(const float* __restrict__ e1, const float* __restrict__ e2,
                         const float* __restrict__ e3, const float* __restrict__ s1,
                         const float* __restrict__ s2, const float* __restrict__ h1,
                         const float* __restrict__ h2, unsigned short* __restrict__ dst) {
  int i4 = blockIdx.x * 256 + threadIdx.x;
  const float* src;
  int rel;
  if (i4 < 786432) {
    if (i4 < 262144) { src = e1; rel = i4; }
    else             { src = e2; rel = i4 - 262144; }
  } else if (i4 < 1146880) {
    if (i4 < 819200) { src = e3; rel = i4 - 786432; }
    else             { src = s1; rel = i4 - 819200; }
  } else if (i4 < 2064384) {
    if (i4 < 1671168) { src = s2; rel = i4 - 1146880; }
    else              { src = h1; rel = i4 - 1671168; }
  } else { src = h2; rel = i4 - 2064384; }
  float4 v = ((const float4*)src)[rel];
  ushort4 o = {f2bf(v.x), f2bf(v.y), f2bf(v.z), f2bf(v.w)};
  ((ushort4*)dst)[i4] = o;
}

// ---------------- cast x [B,512] fp32 into z[:,128:640] bf16 (ld 640)
__global__ void cast_x(const float* __restrict__ x, unsigned short* __restrict__ z) {
  int i = blockIdx.x * blockDim.x + threadIdx.x;  // over B*128
  int b = i >> 7;
  int c = (i & 127) << 2;
  float4 v = *(const float4*)&x[(size_t)b * 512 + c];
  ushort4 o = {f2bf(v.x), f2bf(v.y), f2bf(v.z), f2bf(v.w)};
  *(ushort4*)&z[(size_t)b * 640 + 128 + c] = o;
}

// ---------------- expert sort: histogram of group_idx
__global__ void hist(const int* __restrict__ gidx, int* __restrict__ cnt) {
  __shared__ int lc[3];
  if (threadIdx.x < 3) lc[threadIdx.x] = 0;
  __syncthreads();
  int i = blockIdx.x * 256 + threadIdx.x;
  atomicAdd(&lc[gidx[i]], 1);
  __syncthreads();
  if (threadIdx.x < 3) atomicAdd(&cnt[threadIdx.x], lc[threadIdx.x]);
}

// ---------------- expert sort: padded segment starts + per-tile expert table
__global__ void plan(const int* __restrict__ cnt, int* __restrict__ ps,
                     int* __restrict__ vend, int* __restrict__ texp) {
  __shared__ int sp[4];
  if (threadIdx.x == 0) {
    int p = 0;
    for (int e = 0; e < 3; ++e) {
      sp[e] = p; ps[e] = p; vend[e] = p + cnt[e];
      p += ((cnt[e] + 127) >> 7) << 7;
    }
    sp[3] = p;
  }
  __syncthreads();
  int mt = threadIdx.x;
  if (mt < MT_H) {
    int r0 = mt << 7, e = -1;
    for (int k = 0; k < 3; ++k)
      if (r0 >= sp[k] && r0 < sp[k + 1]) e = k;
    texp[mt] = e;
  }
}

// ---------------- expert sort: scatter row indices into sorted positions
__global__ void scatter(const int* __restrict__ gidx, const int* __restrict__ ps,
                        int* __restrict__ fill, int* __restrict__ perm) {
  int i = blockIdx.x * 256 + threadIdx.x;
  int e = gidx[i];
  int pos = ps[e] + atomicAdd(&fill[e], 1);
  perm[pos] = i;
}

// ---------------- gather hidden rows into expert-sorted ht [MT_H*128, 1024]
// (pad / out-of-range rows -> zeros)
__global__ void gather_h(const unsigned short* __restrict__ hid, const int* __restrict__ perm,
                         const int* __restrict__ texp, const int* __restrict__ vend,
                         unsigned short* __restrict__ ht) {
  int idx = blockIdx.x * 256 + threadIdx.x;  // over MT_H*128*128
  int p = idx >> 7, c8 = (idx & 127) << 3;
  int e = texp[p >> 7];
  uint4 v = {0u, 0u, 0u, 0u};
  if (e >= 0 && p < vend[e]) {
    int src = perm[p];
    v = *(const uint4*)&hid[(size_t)src * 1024 + c8];
  }
  *(uint4*)&ht[(size_t)p * 1024 + c8] = v;
}

// ---------------- final: per sorted row p, dot(t2p[p,:], w3[e]) + b3[e], softplus,
// write to ORIGINAL row perm[p]
__global__ void final_pred(const unsigned short* __restrict__ t2, const int* __restrict__ perm,
                           const int* __restrict__ texp, const int* __restrict__ vend,
                           const float* __restrict__ w3, const float* __restrict__ b3,
                           float* __restrict__ out) {
  int p = blockIdx.x * 4 + (threadIdx.x >> 6);
  int l = threadIdx.x & 63;
  int e = texp[p >> 7];
  if (e < 0 || p >= vend[e]) return;
  ushort4 u = *(const ushort4*)&t2[(size_t)p * 256 + l * 4];
  float4 wv = *(const float4*)&w3[e * 256 + l * 4];
  float sum = bf2f(u.x) * wv.x + bf2f(u.y) * wv.y + bf2f(u.z) * wv.z + bf2f(u.w) * wv.w;
#pragma unroll
  for (int off = 32; off; off >>= 1) sum += __shfl_down(sum, off, 64);
  if (l == 0) {
    int orig = perm[p];
    float xr = sum + b3[e];
    float sp = (xr > 0.f) ? (xr + log1pf(expf(-xr))) : log1pf(expf(xr));
    float pl = -sp;
    out[orig] = pl;
    out[B_ + orig] = expf(pl * LN10_);
  }
}

extern "C" void kernel_launch(void* const* d_in, const int* in_sizes, int n_in,
                              void* d_out, int out_size, void* d_ws, size_t ws_size,
                              hipStream_t stream) {
  const float* x    = (const float*)d_in[0];
  const int*   gidx = (const int*)d_in[1];
  const float* e_w1 = (const float*)d_in[2];
  const float* e_g1 = (const float*)d_in[4];
  const float* e_be1= (const float*)d_in[5];
  const float* e_w2 = (const float*)d_in[6];
  const float* e_g2 = (const float*)d_in[8];
  const float* e_be2= (const float*)d_in[9];
  const float* e_w3 = (const float*)d_in[10];
  const float* e_b3 = (const float*)d_in[11];
  const float* s_w1 = (const float*)d_in[12];
  const float* s_g1 = (const float*)d_in[14];
  const float* s_be1= (const float*)d_in[15];
  const float* s_w2 = (const float*)d_in[16];
  const float* s_g2 = (const float*)d_in[18];
  const float* s_be2= (const float*)d_in[19];
  const float* h_w1 = (const float*)d_in[20];
  const float* h_b1 = (const float*)d_in[21];
  const float* h_w2 = (const float*)d_in[22];
  const float* h_b2 = (const float*)d_in[23];
  const float* h_w3 = (const float*)d_in[24];
  const float* h_b3 = (const float*)d_in[25];
  float* out = (float*)d_out;

  char* ws = (char*)d_ws;
  size_t off = 0;
  auto alloc = [&](size_t bytes) -> char* {
    char* p = ws + off;
    off += (bytes + 255) & ~(size_t)255;
    return p;
  };
  // bf16 weight buffers MUST stay contiguous & in this order (cast_all table)
  unsigned short* wb_e1 = (unsigned short*)alloc((size_t)2048 * 512 * 2);
  unsigned short* wb_e2 = (unsigned short*)alloc((size_t)1024 * 2048 * 2);
  unsigned short* wb_e3 = (unsigned short*)alloc((size_t)128 * 1024 * 2);
  unsigned short* wb_s1 = (unsigned short*)alloc((size_t)2048 * 640 * 2);
  unsigned short* wb_s2 = (unsigned short*)alloc((size_t)1024 * 2048 * 2);
  unsigned short* wb_h1 = (unsigned short*)alloc((size_t)3 * 512 * 1024 * 2);
  unsigned short* wb_h2 = (unsigned short*)alloc((size_t)3 * 256 * 512 * 2);
  unsigned short* z     = (unsigned short*)alloc((size_t)B_ * 640 * 2);
  unsigned short* bufA  = (unsigned short*)alloc((size_t)B_ * 2048 * 2);
  unsigned short* bufB  = (unsigned short*)alloc((size_t)B_ * 1024 * 2);
  // stats + counters (one memset region): st 12288 floats, cnt[3], fill[3]
  float* st = (float*)alloc(12288 * sizeof(float) + 64);
  int* cnt  = (int*)(st + 12288);
  int* fill = cnt + 3;
  float* st0 = st;            // e1: 2*2048
  float* st1 = st + 4096;     // e2: 2*1024
  float* st2 = st + 6144;     // s1: 2*2048
  float* st3 = st + 10240;    // s2: 2*1024
  // sort plan (written before read each call; no memset needed)
  int* ps   = (int*)alloc(4 * sizeof(int));
  int* vend = (int*)alloc(3 * sizeof(int));
  int* texp = (int*)alloc(MT_H * sizeof(int));
  int* perm = (int*)alloc((size_t)MT_H * 128 * sizeof(int));
  // head buffers carved from dead regions:
  unsigned short* ht  = bufA;                                    // [MT_H*128,1024] 69.2 MB
  unsigned short* t1p = bufA + (size_t)MT_H * 128 * 1024;        // [MT_H*128, 512] 34.6 MB (tot<134MB)
  unsigned short* t2p = z;                                       // [MT_H*128, 256] 17.3 MB (z dead then)

  cast_all<<<8448, 256, 0, stream>>>(e_w1, e_w2, e_w3, s_w1, s_w2, h_w1, h_w2, wb_e1);
  cast_x<<<(B_ * 128) / 256, 256, 0, stream>>>(x, z);
  hipMemsetAsync(st, 0, 12288 * sizeof(float) + 64, stream);
  // expert sort plan (independent of trunk; do it early)
  hist<<<B_ / 256, 256, 0, stream>>>(gidx, cnt);
  plan<<<1, 512, 0, stream>>>(cnt, ps, vend, texp);
  scatter<<<B_ / 256, 256, 0, stream>>>(gidx, ps, fill, perm);

  // encoder L1: [B,512] x [2048,512]^T -> bufA  (BN stats fused)
  gemm_bt<<<dim3(16, 256), 256, 0, stream>>>(z + 128, 640, wb_e1, 512, bufA, 2048, 512,
                                             nullptr, 0, st0, 2048, 0, 0, 0, 0, nullptr);
  bn_apply<<<B_, 256, 0, stream>>>(bufA, st0, e_g1, e_be1, 2048, 1.0f / B_);
  // encoder L2: [B,2048] x [1024,2048]^T -> bufB
  gemm_bt<<<dim3(8, 256), 256, 0, stream>>>(bufA, 2048, wb_e2, 2048, bufB, 1024, 2048,
                                            nullptr, 0, st1, 1024, 0, 0, 0, 0, nullptr);
  bn_apply<<<B_ / 2, 256, 0, stream>>>(bufB, st1, e_g2, e_be2, 1024, 1.0f / B_);
  // latent: [B,1024] x [128,1024]^T -> z[:,0:128] (ldc 640), +e_b3
  gemm_bt<<<dim3(1, 256), 256, 0, stream>>>(bufB, 1024, wb_e3, 1024, z, 640, 1024,
                                            e_b3, 0, nullptr, 0, 0, 0, 0, 0, nullptr);
  // shared L1: [B,640] x [2048,640]^T -> bufA
  gemm_bt<<<dim3(16, 256), 256, 0, stream>>>(z, 640, wb_s1, 640, bufA, 2048, 640,
                                             nullptr, 0, st2, 2048, 0, 0, 0, 0, nullptr);
  bn_apply<<<B_, 256, 0, stream>>>(bufA, st2, s_g1, s_be1, 2048, 1.0f / B_);
  // shared L2: [B,2048] x [1024,2048]^T -> bufB (= hidden)
  gemm_bt<<<dim3(8, 256), 256, 0, stream>>>(bufA, 2048, wb_s2, 2048, bufB, 1024, 2048,
                                            nullptr, 0, st3, 1024, 0, 0, 0, 0, nullptr);
  bn_apply<<<B_ / 2, 256, 0, stream>>>(bufB, st3, s_g2, s_be2, 1024, 1.0f / B_);

  // gather hidden into expert-sorted ht (bufA dead after s2's A-read)
  gather_h<<<(MT_H * 128 * 128) / 256, 256, 0, stream>>>(bufB, perm, texp, vend, ht);

  // head L1, expert-sparse: t1p = elu(ht @ h_w1[e(mt)]^T + h_b1[e]) [Mp,512]
  gemm_bt<<<dim3(4, MT_H), 256, 0, stream>>>(ht, 1024, wb_h1, 1024, t1p, 512, 1024,
                                             h_b1, 1, nullptr, 0,
                                             0, (long)512 * 1024, 0, 512, texp);
  // head L2, expert-sparse: t2p = elu(t1p @ h_w2[e(mt)]^T + h_b2[e]) [Mp,256]
  gemm_bt<<<dim3(2, MT_H), 256, 0, stream>>>(t1p, 512, wb_h2, 512, t2p, 256, 512,
                                             h_b2, 1, nullptr, 0,
                                             0, (long)256 * 512, 0, 256, texp);

  final_pred<<<(MT_H * 128) / 4, 256, 0, stream>>>(t2p, perm, texp, vend, h_w3, h_b3, out);
}

// Round 7
// 1150.077 us; speedup vs baseline: 1.1863x; 1.1863x over previous
//
#include <hip/hip_runtime.h>
#include <math.h>

#define B_    32768
#define LN10_ 2.302585092994046f
#define MT_H  264   // padded m-tile count for sorted head GEMMs (>= 258 worst case)
#define NBLK  128   // B_/256 sort blocks

typedef __attribute__((ext_vector_type(8))) short short8;
typedef __attribute__((ext_vector_type(4))) float f32x4;

typedef const __attribute__((address_space(1))) void gvoid_t;
typedef __attribute__((address_space(3))) void svoid_t;

__device__ __forceinline__ void gl16(const void* g, void* l) {
  __builtin_amdgcn_global_load_lds((gvoid_t*)g, (svoid_t*)l, 16, 0, 0);
}

__device__ __forceinline__ float bf2f(unsigned int u) {
  union { unsigned int i; float f; } v; v.i = u << 16; return v.f;
}
// round-to-nearest-even f32 -> bf16 (finite inputs)
__device__ __forceinline__ unsigned short f2bf(float f) {
  union { float f; unsigned int i; } v; v.f = f;
  unsigned int x = v.i;
  unsigned int r = x + 0x7FFFu + ((x >> 16) & 1u);
  return (unsigned short)(r >> 16);
}

// ---------------- GEMM: C[m,n] = sum_k A[m,k] * W[n,k]  (+bias, +elu, +col-stats)
// bf16 in/out, fp32 acc. grid: (N/128, Mtiles, E), block 256. Tile 128x128x64.
// LDS XOR swizzle (R4: SQ_LDS_BANK_CONFLICT 5e7 -> 0).
// XCD block swizzle (R4: big-GEMM FETCH 532 -> 131 MB ~= ideal); needs ny%8==0.
// Expert selection: e = texp ? texp[mt] : blockIdx.z; e<0 -> whole block exits.
__global__ __launch_bounds__(256)
void gemm_bt(const unsigned short* __restrict__ A0, int lda,
             const unsigned short* __restrict__ W0, int ldw,
             unsigned short* __restrict__ C0, int ldc,
             int K, const float* __restrict__ bias0, int elu,
             float* __restrict__ st, int Ntot,
             long eA, long eW, long eC, int eBias,
             const int* __restrict__ texp) {
  __shared__ __align__(16) unsigned short lA[128 * 64];
  __shared__ __align__(16) unsigned short lB[128 * 64];
  const int t = threadIdx.x;
  const int nx = gridDim.x, ny = gridDim.y;
  const int f = blockIdx.y * nx + blockIdx.x;
  const int xcd = f & 7, g = f >> 3;
  const int gdiv = g / nx;
  const int mt = xcd * (ny >> 3) + gdiv;
  const int nt = g - gdiv * nx;
  const int mBase = mt * 128;
  const int nBase = nt * 128;
  int e = texp ? texp[mt] : (int)blockIdx.z;
  if (e < 0) return;  // pad tile, uniform exit
  const unsigned short* A = A0 + (size_t)e * eA;
  const unsigned short* W = W0 + (size_t)e * eW;
  unsigned short* C = C0 + (size_t)e * eC;
  const float* bias = bias0 ? (bias0 + (size_t)e * eBias) : nullptr;
  const unsigned short* Ap = A + (size_t)mBase * lda;
  const unsigned short* Wp = W + (size_t)nBase * ldw;
  const int w = t >> 6, l = t & 63;
  const int wr = (w >> 1) * 64, wc = (w & 1) * 64;
  const int lm = l & 15, lg = l >> 4;

  f32x4 acc[4][4];
#pragma unroll
  for (int i = 0; i < 4; ++i)
#pragma unroll
    for (int j = 0; j < 4; ++j) {
      f32x4 z4 = {0.f, 0.f, 0.f, 0.f};
      acc[i][j] = z4;
    }

  for (int k0 = 0; k0 < K; k0 += 64) {
    __syncthreads();
#pragma unroll
    for (int it = 0; it < 4; ++it) {
      int chunk = it * 256 + t;
      int row = chunk >> 3, sc = chunk & 7;
      int gc = (sc ^ (row & 7)) << 3;  // swizzled source chunk (element offset)
      gl16(Ap + (size_t)row * lda + k0 + gc, &lA[chunk * 8]);
      gl16(Wp + (size_t)row * ldw + k0 + gc, &lB[chunk * 8]);
    }
    __syncthreads();
#pragma unroll
    for (int kk = 0; kk < 64; kk += 32) {
      short8 af[4], bfr[4];
#pragma unroll
      for (int i = 0; i < 4; ++i) {
        int ar = wr + i * 16 + lm;
        int ac = (kk >> 3) + lg;
        af[i] = *(const short8*)&lA[ar * 64 + ((ac ^ (ar & 7)) << 3)];
      }
#pragma unroll
      for (int j = 0; j < 4; ++j) {
        int br = wc + j * 16 + lm;
        int bc = (kk >> 3) + lg;
        bfr[j] = *(const short8*)&lB[br * 64 + ((bc ^ (br & 7)) << 3)];
      }
#pragma unroll
      for (int i = 0; i < 4; ++i)
#pragma unroll
        for (int j = 0; j < 4; ++j)
          acc[i][j] = __builtin_amdgcn_mfma_f32_16x16x32_bf16(af[i], bfr[j], acc[i][j], 0, 0, 0);
    }
  }

  // epilogue: D row = (lane>>4)*4 + reg, col = lane&15
#pragma unroll
  for (int j = 0; j < 4; ++j) {
    int n = nBase + wc + j * 16 + lm;
    float bj = bias ? bias[n] : 0.f;
    float s = 0.f, q = 0.f;
#pragma unroll
    for (int i = 0; i < 4; ++i) {
      int m0 = mBase + wr + i * 16 + lg * 4;
#pragma unroll
      for (int r = 0; r < 4; ++r) {
        float v = acc[i][j][r] + bj;
        if (elu) v = v > 0.f ? v : expm1f(v);
        s += v; q += v * v;
        C[(size_t)(m0 + r) * ldc + n] = f2bf(v);
      }
    }
    if (st) {
      s += __shfl_xor(s, 16, 64); s += __shfl_xor(s, 32, 64);
      q += __shfl_xor(q, 16, 64); q += __shfl_xor(q, 32, 64);
      if (lg == 0) { atomicAdd(&st[n], s); atomicAdd(&st[Ntot + n], q); }
    }
  }
}

// ---------------- in-place BN + ELU on bf16 [B,N], 8 elems/thread (N pow2)
__global__ void bn_apply(unsigned short* __restrict__ Y, const float* __restrict__ st,
                         const float* __restrict__ gam, const float* __restrict__ bet,
                         int N, float invB) {
  size_t i = (size_t)blockIdx.x * blockDim.x + threadIdx.x;
  size_t base = i * 8;
  int col = (int)(base & (size_t)(N - 1));
  float a8[8], b8[8];
#pragma unroll
  for (int k = 0; k < 8; ++k) {
    int c = col + k;
    float m = st[c] * invB;
    float var = st[N + c] * invB - m * m;
    float av = gam[c] * rsqrtf(var + 1e-5f);
    a8[k] = av;
    b8[k] = bet[c] - m * av;
  }
  uint4 u = *(uint4*)&Y[base];
  unsigned int uu[4] = {u.x, u.y, u.z, u.w};
  unsigned int oo[4];
#pragma unroll
  for (int k = 0; k < 4; ++k) {
    float vlo = bf2f(uu[k] & 0xFFFFu);
    float vhi = bf2f(uu[k] >> 16);
    float flo = a8[2 * k] * vlo + b8[2 * k];
    float fhi = a8[2 * k + 1] * vhi + b8[2 * k + 1];
    flo = flo > 0.f ? flo : expm1f(flo);
    fhi = fhi > 0.f ? fhi : expm1f(fhi);
    oo[k] = (unsigned int)f2bf(flo) | ((unsigned int)f2bf(fhi) << 16);
  }
  uint4 o = {oo[0], oo[1], oo[2], oo[3]};
  *(uint4*)&Y[base] = o;
}

// ---------------- cast ALL weights fp32->bf16 in one launch (region table in
// float4 units; dst bf16 buffers contiguous in same order)
__global__ void cast_all(const float* __restrict__ e1, const float* __restrict__ e2,
                         const float* __restrict__ e3, const float* __restrict__ s1,
                         const float* __restrict__ s2, const float* __restrict__ h1,
                         const float* __restrict__ h2, unsigned short* __restrict__ dst) {
  int i4 = blockIdx.x * 256 + threadIdx.x;
  const float* src;
  int rel;
  if (i4 < 786432) {
    if (i4 < 262144) { src = e1; rel = i4; }
    else             { src = e2; rel = i4 - 262144; }
  } else if (i4 < 1146880) {
    if (i4 < 819200) { src = e3; rel = i4 - 786432; }
    else             { src = s1; rel = i4 - 819200; }
  } else if (i4 < 2064384) {
    if (i4 < 1671168) { src = s2; rel = i4 - 1146880; }
    else              { src = h1; rel = i4 - 1671168; }
  } else { src = h2; rel = i4 - 2064384; }
  float4 v = ((const float4*)src)[rel];
  ushort4 o = {f2bf(v.x), f2bf(v.y), f2bf(v.z), f2bf(v.w)};
  ((ushort4*)dst)[i4] = o;
}

// ---------------- cast x [B,512] fp32 into z[:,128:640] bf16 (ld 640)
__global__ void cast_x(const float* __restrict__ x, unsigned short* __restrict__ z) {
  int i = blockIdx.x * blockDim.x + threadIdx.x;  // over B*128
  int b = i >> 7;
  int c = (i & 127) << 2;
  float4 v = *(const float4*)&x[(size_t)b * 512 + c];
  ushort4 o = {f2bf(v.x), f2bf(v.y), f2bf(v.z), f2bf(v.w)};
  *(ushort4*)&z[(size_t)b * 640 + 128 + c] = o;
}

// ---------------- sort step 1: per-block expert counts via wave ballots (NO atomics)
__global__ void hist_blocks(const int* __restrict__ gidx, int* __restrict__ bcnt) {
  int blk = blockIdx.x;
  int i = blk * 256 + threadIdx.x;
  int e = gidx[i];
  int l = threadIdx.x & 63, w = threadIdx.x >> 6;
  __shared__ int wc[4][3];
  unsigned long long m0 = __ballot(e == 0);
  unsigned long long m1 = __ballot(e == 1);
  unsigned long long m2 = __ballot(e == 2);
  if (l == 0) { wc[w][0] = __popcll(m0); wc[w][1] = __popcll(m1); wc[w][2] = __popcll(m2); }
  __syncthreads();
  if (threadIdx.x < 3)
    bcnt[blk * 3 + threadIdx.x] = wc[0][threadIdx.x] + wc[1][threadIdx.x] +
                                  wc[2][threadIdx.x] + wc[3][threadIdx.x];
}

// ---------------- sort step 2: one block; segment starts, vend, texp, and
// per-block exclusive offsets boff[blk][e] (serial 128-scan per expert by 3 threads)
__global__ void scan_plan(const int* __restrict__ bcnt, int* __restrict__ boff,
                          int* __restrict__ vend, int* __restrict__ texp) {
  __shared__ int sp[4];
  __shared__ int cnt[3];
  int t = threadIdx.x;
  if (t < 3) {
    int s = 0;
    for (int b = 0; b < NBLK; ++b) s += bcnt[b * 3 + t];
    cnt[t] = s;
  }
  __syncthreads();
  if (t == 0) {
    int p = 0;
    for (int e = 0; e < 3; ++e) {
      sp[e] = p; vend[e] = p + cnt[e];
      p += ((cnt[e] + 127) >> 7) << 7;
    }
    sp[3] = p;
  }
  __syncthreads();
  if (t < 3) {
    int run = sp[t];
    for (int b = 0; b < NBLK; ++b) { boff[b * 3 + t] = run; run += bcnt[b * 3 + t]; }
  }
  if (t < MT_H) {
    int r0 = t << 7, e = -1;
    for (int k = 0; k < 3; ++k)
      if (r0 >= sp[k] && r0 < sp[k + 1]) e = k;
    texp[t] = e;
  }
}

// ---------------- sort step 3: scatter via ballot-rank (NO atomics, stable)
__global__ void scatter2(const int* __restrict__ gidx, const int* __restrict__ boff,
                         int* __restrict__ perm) {
  int blk = blockIdx.x;
  int i = blk * 256 + threadIdx.x;
  int e = gidx[i];
  int l = threadIdx.x & 63, w = threadIdx.x >> 6;
  __shared__ int wc[4][3];
  unsigned long long m0 = __ballot(e == 0);
  unsigned long long m1 = __ballot(e == 1);
  unsigned long long m2 = __ballot(e == 2);
  if (l == 0) { wc[w][0] = __popcll(m0); wc[w][1] = __popcll(m1); wc[w][2] = __popcll(m2); }
  __syncthreads();
  unsigned long long me = (e == 0) ? m0 : ((e == 1) ? m1 : m2);
  int rank = __popcll(me & ((1ull << l) - 1ull));
  int woff = 0;
  for (int ww = 0; ww < w; ++ww) woff += wc[ww][e];
  perm[boff[blk * 3 + e] + woff + rank] = i;
}

// ---------------- gather hidden rows into expert-sorted ht [MT_H*128, 1024]
__global__ void gather_h(const unsigned short* __restrict__ hid, const int* __restrict__ perm,
                         const int* __restrict__ texp, const int* __restrict__ vend,
                         unsigned short* __restrict__ ht) {
  int idx = blockIdx.x * 256 + threadIdx.x;  // over MT_H*128*128
  int p = idx >> 7, c8 = (idx & 127) << 3;
  int e = texp[p >> 7];
  uint4 v = {0u, 0u, 0u, 0u};
  if (e >= 0 && p < vend[e]) {
    int src = perm[p];
    v = *(const uint4*)&hid[(size_t)src * 1024 + c8];
  }
  *(uint4*)&ht[(size_t)p * 1024 + c8] = v;
}

// ---------------- final: per sorted row p, dot(t2p[p,:], w3[e]) + b3[e], softplus,
// write to ORIGINAL row perm[p]
__global__ void final_pred(const unsigned short* __restrict__ t2, const int* __restrict__ perm,
                           const int* __restrict__ texp, const int* __restrict__ vend,
                           const float* __restrict__ w3, const float* __restrict__ b3,
                           float* __restrict__ out) {
  int p = blockIdx.x * 4 + (threadIdx.x >> 6);
  int l = threadIdx.x & 63;
  int e = texp[p >> 7];
  if (e < 0 || p >= vend[e]) return;
  ushort4 u = *(const ushort4*)&t2[(size_t)p * 256 + l * 4];
  float4 wv = *(const float4*)&w3[e * 256 + l * 4];
  float sum = bf2f(u.x) * wv.x + bf2f(u.y) * wv.y + bf2f(u.z) * wv.z + bf2f(u.w) * wv.w;
#pragma unroll
  for (int off = 32; off; off >>= 1) sum += __shfl_down(sum, off, 64);
  if (l == 0) {
    int orig = perm[p];
    float xr = sum + b3[e];
    float sp = (xr > 0.f) ? (xr + log1pf(expf(-xr))) : log1pf(expf(xr));
    float pl = -sp;
    out[orig] = pl;
    out[B_ + orig] = expf(pl * LN10_);
  }
}

extern "C" void kernel_launch(void* const* d_in, const int* in_sizes, int n_in,
                              void* d_out, int out_size, void* d_ws, size_t ws_size,
                              hipStream_t stream) {
  const float* x    = (const float*)d_in[0];
  const int*   gidx = (const int*)d_in[1];
  const float* e_w1 = (const float*)d_in[2];
  const float* e_g1 = (const float*)d_in[4];
  const float* e_be1= (const float*)d_in[5];
  const float* e_w2 = (const float*)d_in[6];
  const float* e_g2 = (const float*)d_in[8];
  const float* e_be2= (const float*)d_in[9];
  const float* e_w3 = (const float*)d_in[10];
  const float* e_b3 = (const float*)d_in[11];
  const float* s_w1 = (const float*)d_in[12];
  const float* s_g1 = (const float*)d_in[14];
  const float* s_be1= (const float*)d_in[15];
  const float* s_w2 = (const float*)d_in[16];
  const float* s_g2 = (const float*)d_in[18];
  const float* s_be2= (const float*)d_in[19];
  const float* h_w1 = (const float*)d_in[20];
  const float* h_b1 = (const float*)d_in[21];
  const float* h_w2 = (const float*)d_in[22];
  const float* h_b2 = (const float*)d_in[23];
  const float* h_w3 = (const float*)d_in[24];
  const float* h_b3 = (const float*)d_in[25];
  float* out = (float*)d_out;

  char* ws = (char*)d_ws;
  size_t off = 0;
  auto alloc = [&](size_t bytes) -> char* {
    char* p = ws + off;
    off += (bytes + 255) & ~(size_t)255;
    return p;
  };
  // bf16 weight buffers MUST stay contiguous & in this order (cast_all table)
  unsigned short* wb_e1 = (unsigned short*)alloc((size_t)2048 * 512 * 2);
  unsigned short* wb_e2 = (unsigned short*)alloc((size_t)1024 * 2048 * 2);
  unsigned short* wb_e3 = (unsigned short*)alloc((size_t)128 * 1024 * 2);
  unsigned short* wb_s1 = (unsigned short*)alloc((size_t)2048 * 640 * 2);
  unsigned short* wb_s2 = (unsigned short*)alloc((size_t)1024 * 2048 * 2);
  unsigned short* wb_h1 = (unsigned short*)alloc((size_t)3 * 512 * 1024 * 2);
  unsigned short* wb_h2 = (unsigned short*)alloc((size_t)3 * 256 * 512 * 2);
  unsigned short* z     = (unsigned short*)alloc((size_t)B_ * 640 * 2);
  unsigned short* bufA  = (unsigned short*)alloc((size_t)B_ * 2048 * 2);
  unsigned short* bufB  = (unsigned short*)alloc((size_t)B_ * 1024 * 2);
  // BN stats (memset each call)
  float* st = (float*)alloc(12288 * sizeof(float));
  float* st0 = st;            // e1: 2*2048
  float* st1 = st + 4096;     // e2: 2*1024
  float* st2 = st + 6144;     // s1: 2*2048
  float* st3 = st + 10240;    // s2: 2*1024
  // sort plan (all written before read each call; no memset needed)
  int* bcnt = (int*)alloc(NBLK * 3 * sizeof(int));
  int* boff = (int*)alloc(NBLK * 3 * sizeof(int));
  int* vend = (int*)alloc(3 * sizeof(int));
  int* texp = (int*)alloc(MT_H * sizeof(int));
  int* perm = (int*)alloc((size_t)MT_H * 128 * sizeof(int));
  // head buffers carved from dead regions:
  unsigned short* ht  = bufA;                                    // [MT_H*128,1024]
  unsigned short* t1p = bufA + (size_t)MT_H * 128 * 1024;        // [MT_H*128, 512]
  unsigned short* t2p = z;                                       // [MT_H*128, 256] (z dead then)

  cast_all<<<8448, 256, 0, stream>>>(e_w1, e_w2, e_w3, s_w1, s_w2, h_w1, h_w2, wb_e1);
  cast_x<<<(B_ * 128) / 256, 256, 0, stream>>>(x, z);
  hipMemsetAsync(st, 0, 12288 * sizeof(float), stream);
  // expert sort plan — deterministic, atomic-free
  hist_blocks<<<NBLK, 256, 0, stream>>>(gidx, bcnt);
  scan_plan<<<1, 512, 0, stream>>>(bcnt, boff, vend, texp);
  scatter2<<<NBLK, 256, 0, stream>>>(gidx, boff, perm);

  // encoder L1: [B,512] x [2048,512]^T -> bufA  (BN stats fused)
  gemm_bt<<<dim3(16, 256), 256, 0, stream>>>(z + 128, 640, wb_e1, 512, bufA, 2048, 512,
                                             nullptr, 0, st0, 2048, 0, 0, 0, 0, nullptr);
  bn_apply<<<B_, 256, 0, stream>>>(bufA, st0, e_g1, e_be1, 2048, 1.0f / B_);
  // encoder L2: [B,2048] x [1024,2048]^T -> bufB
  gemm_bt<<<dim3(8, 256), 256, 0, stream>>>(bufA, 2048, wb_e2, 2048, bufB, 1024, 2048,
                                            nullptr, 0, st1, 1024, 0, 0, 0, 0, nullptr);
  bn_apply<<<B_ / 2, 256, 0, stream>>>(bufB, st1, e_g2, e_be2, 1024, 1.0f / B_);
  // latent: [B,1024] x [128,1024]^T -> z[:,0:128] (ldc 640), +e_b3
  gemm_bt<<<dim3(1, 256), 256, 0, stream>>>(bufB, 1024, wb_e3, 1024, z, 640, 1024,
                                            e_b3, 0, nullptr, 0, 0, 0, 0, 0, nullptr);
  // shared L1: [B,640] x [2048,640]^T -> bufA
  gemm_bt<<<dim3(16, 256), 256, 0, stream>>>(z, 640, wb_s1, 640, bufA, 2048, 640,
                                             nullptr, 0, st2, 2048, 0, 0, 0, 0, nullptr);
  bn_apply<<<B_, 256, 0, stream>>>(bufA, st2, s_g1, s_be1, 2048, 1.0f / B_);
  // shared L2: [B,2048] x [1024,2048]^T -> bufB (= hidden)
  gemm_bt<<<dim3(8, 256), 256, 0, stream>>>(bufA, 2048, wb_s2, 2048, bufB, 1024, 2048,
                                            nullptr, 0, st3, 1024, 0, 0, 0, 0, nullptr);
  bn_apply<<<B_ / 2, 256, 0, stream>>>(bufB, st3, s_g2, s_be2, 1024, 1.0f / B_);

  // gather hidden into expert-sorted ht (bufA dead after s2's A-read)
  gather_h<<<(MT_H * 128 * 128) / 256, 256, 0, stream>>>(bufB, perm, texp, vend, ht);

  // head L1, expert-sparse: t1p = elu(ht @ h_w1[e(mt)]^T + h_b1[e]) [Mp,512]
  gemm_bt<<<dim3(4, MT_H), 256, 0, stream>>>(ht, 1024, wb_h1, 1024, t1p, 512, 1024,
                                             h_b1, 1, nullptr, 0,
                                             0, (long)512 * 1024, 0, 512, texp);
  // head L2, expert-sparse: t2p = elu(t1p @ h_w2[e(mt)]^T + h_b2[e]) [Mp,256]
  gemm_bt<<<dim3(2, MT_H), 256, 0, stream>>>(t1p, 512, wb_h2, 512, t2p, 256, 512,
                                             h_b2, 1, nullptr, 0,
                                             0, (long)256 * 512, 0, 256, texp);

  final_pred<<<(MT_H * 128) / 4, 256, 0, stream>>>(t2p, perm, texp, vend, h_w3, h_b3, out);
}